// Round 2
// baseline (401.195 us; speedup 1.0000x reference)
//
#include <hip/hip_runtime.h>
#include <hip/hip_bf16.h>

// N=64, C=O=64, T=300, V=25, S=3, E=12 ; BN eval, gamma=1e-6 -> attention
// branch may be computed in bf16 (error ~1e-8 absolute on output).

typedef short v4s __attribute__((ext_vector_type(4)));
typedef float v4f __attribute__((ext_vector_type(4)));

__device__ __forceinline__ unsigned short f2bf(float f) {
  unsigned u = __builtin_bit_cast(unsigned, f);
  u += 0x7FFFu + ((u >> 16) & 1u);   // RNE; inputs have no NaN
  return (unsigned short)(u >> 16);
}

// ---------------------------------------------------------------------------
// Kernel A: temporal collapse. t1[s,n,c,v] = sum_t x[n,c,t,v]*Wt1[s,t] + bt1[s]
// ---------------------------------------------------------------------------
__global__ __launch_bounds__(256) void k_tcollapse(
    const float* __restrict__ x,
    const float* __restrict__ Wt1, const float* __restrict__ bt1,
    const float* __restrict__ Wt2, const float* __restrict__ bt2,
    float* __restrict__ t1o, float* __restrict__ t2o) {
  __shared__ __attribute__((aligned(16))) float xt[7500];   // [t][v]
  __shared__ float pl[6 * 250];                             // [s6][g][v]
  const int b = blockIdx.x;            // n*64 + c
  const int tid = threadIdx.x;

  const float4* xg = (const float4*)(x + (size_t)b * 7500);
  for (int i = tid; i < 1875; i += 256) ((float4*)xt)[i] = xg[i];
  __syncthreads();

  if (tid < 250) {
    const int v = tid % 25, g = tid / 25;
    float p0 = 0.f, p1 = 0.f, p2 = 0.f, p3 = 0.f, p4 = 0.f, p5 = 0.f;
    const int tbase = g * 30;
    #pragma unroll 5
    for (int j = 0; j < 30; ++j) {
      const int t = tbase + j;
      const float xv = xt[t * 25 + v];
      p0 += xv * Wt1[t];       p1 += xv * Wt1[300 + t];  p2 += xv * Wt1[600 + t];
      p3 += xv * Wt2[t];       p4 += xv * Wt2[300 + t];  p5 += xv * Wt2[600 + t];
    }
    pl[0 * 250 + g * 25 + v] = p0;
    pl[1 * 250 + g * 25 + v] = p1;
    pl[2 * 250 + g * 25 + v] = p2;
    pl[3 * 250 + g * 25 + v] = p3;
    pl[4 * 250 + g * 25 + v] = p4;
    pl[5 * 250 + g * 25 + v] = p5;
  }
  __syncthreads();

  if (tid < 150) {
    const int s6 = tid / 25, v = tid % 25;
    float a = 0.f;
    #pragma unroll
    for (int g = 0; g < 10; ++g) a += pl[s6 * 250 + g * 25 + v];
    const int n = b >> 6, c = b & 63;
    if (s6 < 3) t1o[((s6 * 64 + n) * 64 + c) * 25 + v] = a + bt1[s6];
    else        t2o[(((s6 - 3) * 64 + n) * 64 + c) * 25 + v] = a + bt2[s6 - 3];
  }
}

// ---------------------------------------------------------------------------
// Kernel B: q/k convs + logits + softmax over v. Emits A1^T as bf16, zero-
// padded to [n][s][u:32][v:32]  (rows u>=25 and cols v>=25 are zero).
// ---------------------------------------------------------------------------
__global__ __launch_bounds__(128) void k_attn(
    const float* __restrict__ t1, const float* __restrict__ t2,
    const float* __restrict__ Wq, const float* __restrict__ bq,
    const float* __restrict__ Wk, const float* __restrict__ bk,
    unsigned short* __restrict__ a1t) {
  const int s = blockIdx.x >> 6, n = blockIdx.x & 63;
  __shared__ float q[300], k[300], l[625];
  const int tid = threadIdx.x;

  for (int idx = tid; idx < 300; idx += 128) {
    const int e = idx / 25, v = idx % 25;
    float aq = bq[s * 12 + e], ak = bk[s * 12 + e];
    const float* wq = Wq + (s * 12 + e) * 64;
    const float* wk = Wk + (s * 12 + e) * 64;
    const float* p1 = t1 + (size_t)((s * 64 + n) * 64) * 25 + v;
    const float* p2 = t2 + (size_t)((s * 64 + n) * 64) * 25 + v;
    #pragma unroll 8
    for (int c = 0; c < 64; ++c) {
      aq += wq[c] * p1[c * 25];
      ak += wk[c] * p2[c * 25];
    }
    q[idx] = aq; k[idx] = ak;
  }
  __syncthreads();

  for (int idx = tid; idx < 625; idx += 128) {
    const int v = idx / 25, u = idx % 25;
    float a = 0.f;
    #pragma unroll
    for (int e = 0; e < 12; ++e) a += q[e * 25 + v] * k[e * 25 + u];
    l[idx] = a * (1.0f / 12.0f);
  }
  __syncthreads();

  if (tid < 25) {
    const int u = tid;                       // softmax over v (axis -2)
    float m = -1e30f;
    #pragma unroll
    for (int v = 0; v < 25; ++v) m = fmaxf(m, l[v * 25 + u]);
    float sum = 0.f;
    #pragma unroll
    for (int v = 0; v < 25; ++v) {
      const float e = expf(l[v * 25 + u] - m);
      l[v * 25 + u] = e;
      sum += e;
    }
    const float inv = 1.0f / sum;
    #pragma unroll
    for (int v = 0; v < 25; ++v) l[v * 25 + u] *= inv;
  }
  __syncthreads();

  if (tid < 32) {
    const int u = tid;
    unsigned short* row = a1t + ((size_t)(n * 3 + s) * 32 + u) * 32;
    #pragma unroll
    for (int v = 0; v < 32; ++v) {
      const float val = (u < 25 && v < 25) ? l[v * 25 + u] : 0.f;
      row[v] = f2bf(val);
    }
  }
}

// ---------------------------------------------------------------------------
// Kernel W: Wd'(bf16)[o][s*64+c] = Wd[s][o][c]
// ---------------------------------------------------------------------------
__global__ void k_wdprep(const float* __restrict__ Wd, unsigned short* __restrict__ wdp) {
  const int idx = blockIdx.x * 256 + threadIdx.x;
  if (idx < 12288) {
    const int o = idx / 192, r = idx % 192, s = r >> 6, c = r & 63;
    wdp[idx] = f2bf(Wd[s * 4096 + o * 64 + c]);
  }
}

// ---------------------------------------------------------------------------
// Kernel C (MFMA): per (n, 4-t tile):
//  phase A: B1[(t,c)][u] = sum_v x*A1   (mfma 16x16x16 bf16, K=32 padded)
//  phase B: y[o][(t,u)]  = sum_{s,c} Wd'[o][(s,c)] * B1^T        (K=192)
//  epilogue: relu( y*sc + off + x )  with exact f32 x residual from LDS.
// LDS: x_lds [256][36] f32 (36864B) + b1t [112][200] bf16 (44800B) = 81664B
//      -> 2 blocks/CU.  bn constants live in x_lds spare cols 32/33.
// ---------------------------------------------------------------------------
__global__ __launch_bounds__(256, 2) void k_main(
    const float* __restrict__ x, const unsigned short* __restrict__ a1t,
    const unsigned short* __restrict__ wdp, const float* __restrict__ bd,
    const float* __restrict__ gamma, const float* __restrict__ beta,
    const float* __restrict__ mean, const float* __restrict__ var,
    float* __restrict__ out) {
  __shared__ __attribute__((aligned(16))) char smem[36864 + 44800];
  float* x_lds = (float*)smem;          // [row=t*64+c][36]
  char*  b1t   = smem + 36864;          // [row_tu][200 bf16] stride 400B
  float* y_lds = (float*)b1t;           // overlay after phase B: [j][68] f32

  const int tb = blockIdx.x, n = blockIdx.y;
  const int tid = threadIdx.x;
  const int l = tid & 63, w = tid >> 6, g = l >> 4, lr = l & 15;

  // --- early global fragment loads (no LDS dependency; L2-hot) ---
  // phase-A B operand: A1t[u][v]; lane holds A1[v=kh*16+4g+i][u=nt*16+lr]
  v4s bfrA[3][2][2];
  {
    const unsigned short* ab = a1t + (size_t)(n * 3) * 1024;
    #pragma unroll
    for (int s = 0; s < 3; ++s)
      #pragma unroll
      for (int nt = 0; nt < 2; ++nt)
        #pragma unroll
        for (int kh = 0; kh < 2; ++kh)
          bfrA[s][nt][kh] = *(const v4s*)(ab + s * 1024 + (nt * 16 + lr) * 32 + kh * 16 + 4 * g);
  }
  // phase-B A operand: Wd'[o=w*16+lr][k=kk*16+4g+i]
  v4s wfrB[12];
  #pragma unroll
  for (int kk = 0; kk < 12; ++kk)
    wfrB[kk] = *(const v4s*)(wdp + (w * 16 + lr) * 192 + kk * 16 + 4 * g);

  // --- stage x tile (f32) ---
  const float* xg = x + (size_t)n * 480000 + tb * 100;
  for (int i4 = tid; i4 < 1600; i4 += 256) {
    const int c = i4 / 25, j4 = i4 % 25;
    const float4 vx = *(const float4*)(xg + (size_t)c * 7500 + j4 * 4);
    const float pe[4] = {vx.x, vx.y, vx.z, vx.w};
    #pragma unroll
    for (int e = 0; e < 4; ++e) {
      const int jj = j4 * 4 + e, tt = jj / 25, vv = jj % 25;
      x_lds[(tt * 64 + c) * 36 + vv] = pe[e];
    }
  }
  // zero v-pad cols 25..31 (K padding)
  for (int i = tid; i < 1792; i += 256) {
    const int r = i / 7, col = 25 + i % 7;
    x_lds[r * 36 + col] = 0.f;
  }
  // bn constants into spare cols (rows 0..63, cols 32/33)
  if (tid < 64) {
    const float sc = gamma[tid] * rsqrtf(var[tid] + 1e-5f);
    x_lds[tid * 36 + 32] = sc;
    x_lds[tid * 36 + 33] = (bd[tid] + bd[64 + tid] + bd[128 + tid] - mean[tid]) * sc + beta[tid];
  }
  // zero b1t pad rows 100..111 (stale-LDS insurance)
  for (int i = tid; i < 1200; i += 256) ((unsigned*)(b1t + 40000))[i] = 0;
  __syncthreads();

  // --- phase A: wave w owns t=w; 4 m-tiles (c blocks of 16) ---
  const v4f vzero = {0.f, 0.f, 0.f, 0.f};
  #pragma unroll
  for (int mi = 0; mi < 4; ++mi) {
    const int R = w * 64 + mi * 16 + lr;            // row = t*64+c, c=mi*16+lr
    const float4 xa0 = *(const float4*)&x_lds[R * 36 + 4 * g];
    const float4 xa1 = *(const float4*)&x_lds[R * 36 + 16 + 4 * g];
    v4s a0, a1;
    a0[0] = (short)f2bf(xa0.x); a0[1] = (short)f2bf(xa0.y);
    a0[2] = (short)f2bf(xa0.z); a0[3] = (short)f2bf(xa0.w);
    a1[0] = (short)f2bf(xa1.x); a1[1] = (short)f2bf(xa1.y);
    a1[2] = (short)f2bf(xa1.z); a1[3] = (short)f2bf(xa1.w);
    #pragma unroll
    for (int s = 0; s < 3; ++s) {
      #pragma unroll
      for (int nt = 0; nt < 2; ++nt) {
        v4f d = __builtin_amdgcn_mfma_f32_16x16x16bf16_1k(a0, bfrA[s][nt][0], vzero, 0, 0, 0);
        d = __builtin_amdgcn_mfma_f32_16x16x16bf16_1k(a1, bfrA[s][nt][1], d, 0, 0, 0);
        const int u = nt * 16 + lr;                 // D col -> u ; D rows -> c0..c0+3
        if (u < 25) {
          const unsigned lo = (unsigned)f2bf(d[0]) | ((unsigned)f2bf(d[1]) << 16);
          const unsigned hi = (unsigned)f2bf(d[2]) | ((unsigned)f2bf(d[3]) << 16);
          uint2 pk; pk.x = lo; pk.y = hi;
          *(uint2*)(b1t + (w * 25 + u) * 400 + (s * 64 + mi * 16 + 4 * g) * 2) = pk;
        }
      }
    }
  }
  __syncthreads();

  // --- phase B: wave w owns o-tile [w*16, w*16+16); all 7 (t,u)-tiles ---
  v4f acc[7];
  #pragma unroll
  for (int i = 0; i < 7; ++i) acc[i] = vzero;
  #pragma unroll
  for (int nt2 = 0; nt2 < 7; ++nt2) {
    const int rbase = (nt2 * 16 + lr) * 400;
    #pragma unroll
    for (int kk = 0; kk < 12; ++kk) {
      const v4s bf = *(const v4s*)(b1t + rbase + kk * 32 + g * 8);
      acc[nt2] = __builtin_amdgcn_mfma_f32_16x16x16bf16_1k(wfrB[kk], bf, acc[nt2], 0, 0, 0);
    }
  }
  __syncthreads();                                   // all b1t reads complete

  // --- y into LDS [j=t*25+u][o], stride 68 ---
  #pragma unroll
  for (int nt2 = 0; nt2 < 7; ++nt2) {
    const int j = nt2 * 16 + lr;
    if (j < 100) {
      *(float4*)&y_lds[j * 68 + w * 16 + 4 * g] =
          make_float4(acc[nt2][0], acc[nt2][1], acc[nt2][2], acc[nt2][3]);
    }
  }
  __syncthreads();

  // --- fused epilogue: relu(y*sc + off + x), coalesced float4 writeback ---
  float* og = out + (size_t)n * 480000 + tb * 100;
  for (int i4 = tid; i4 < 1600; i4 += 256) {
    const int c = i4 / 25, j4 = i4 % 25;
    const float sc = x_lds[c * 36 + 32], off = x_lds[c * 36 + 33];
    float r[4];
    #pragma unroll
    for (int e = 0; e < 4; ++e) {
      const int jj = j4 * 4 + e, tt = jj / 25, vv = jj % 25;
      const float xv = x_lds[(tt * 64 + c) * 36 + vv];
      const float yv = y_lds[jj * 68 + c];
      r[e] = fmaxf(yv * sc + off + xv, 0.f);
    }
    *(float4*)(og + (size_t)c * 7500 + j4 * 4) = make_float4(r[0], r[1], r[2], r[3]);
  }
}

// ---------------------------------------------------------------------------
extern "C" void kernel_launch(void* const* d_in, const int* in_sizes, int n_in,
                              void* d_out, int out_size, void* d_ws, size_t ws_size,
                              hipStream_t stream) {
  const float* x     = (const float*)d_in[0];
  const float* Wt1   = (const float*)d_in[1];
  const float* bt1   = (const float*)d_in[2];
  const float* Wt2   = (const float*)d_in[3];
  const float* bt2   = (const float*)d_in[4];
  const float* Wq    = (const float*)d_in[5];
  const float* bq    = (const float*)d_in[6];
  const float* Wk    = (const float*)d_in[7];
  const float* bk    = (const float*)d_in[8];
  const float* Wd    = (const float*)d_in[9];
  const float* bd    = (const float*)d_in[10];
  const float* gamma = (const float*)d_in[11];
  const float* beta  = (const float*)d_in[12];
  const float* mean  = (const float*)d_in[13];
  const float* var   = (const float*)d_in[14];

  float* ws = (float*)d_ws;
  float* t1 = ws;                                   // 307200 f32
  float* t2 = ws + 307200;                          // 307200 f32
  unsigned short* a1t = (unsigned short*)(ws + 614400);      // 196608 u16
  unsigned short* wdp = (unsigned short*)(ws + 614400 + 98304); // 12288 u16
  float* o = (float*)d_out;

  k_wdprep<<<dim3(48), dim3(256), 0, stream>>>(Wd, wdp);
  k_tcollapse<<<dim3(4096), dim3(256), 0, stream>>>(x, Wt1, bt1, Wt2, bt2, t1, t2);
  k_attn<<<dim3(192), dim3(128), 0, stream>>>(t1, t2, Wq, bq, Wk, bk, a1t);
  k_main<<<dim3(75, 64), dim3(256), 0, stream>>>(x, a1t, wdp, bd, gamma, beta, mean, var, o);
}